// Round 18
// baseline (101.728 us; speedup 1.0000x reference)
//
#include <hip/hip_runtime.h>
#include <cstdint>
#include <cstddef>

#define BB 32
#define AA 8400
#define NBB 32
#define CC 80
#define TOPKN 10
#define NCAND (NBB * TOPKN)  // 320 candidate entries per batch

// native clang vector for __builtin_nontemporal_store (HIP float4 is a
// class type the builtin rejects; this alias is layout-identical)
typedef float nfloat4 __attribute__((ext_vector_type(4)));

// ===========================================================================
// K1 (+fused default-fill): per (b,j) block (256t).
// (1) Streams the "unassigned" default output for its 1/1024 slice of the
//     92.5 MB output via NON-TEMPORAL float4 stores (write-once data: bypass
//     L2, keep it for the gathers). Regions (float4 idx, NA=BB*AA):
//     [0,NA/4) labels=clip(gt_labels[b,0]) | [NA/4,NA/4+NA) boxes=gt_boxes[b,0]
//     | scores zeros | fg zeros.
// (2) Analytic candidate enumeration (3-level anchor grid, bit-exact
//     (ix+0.5)*s recompute, exact d>1e-8 re-test) + block top-10 via padded
//     LDS merge ([256][11] u64 rows, stride 88B -> free 2-way aliasing).
//     key = align_bits<<32 | (8400-a): lax.top_k tie semantics.
// ===========================================================================
__global__ __launch_bounds__(256) void gt_topk_kernel(
    const float* __restrict__ pred_scores, const float* __restrict__ pred_boxes,
    const int* __restrict__ gt_labels, const float* __restrict__ gt_boxes,
    const int* __restrict__ gt_mask,
    int* __restrict__ tk, float* __restrict__ out) {
  const int j = blockIdx.x, b = blockIdx.y, t = threadIdx.x;
  const int g = b * NBB + j;

  // ---- fused default-fill (write-only NT stream) ----
  {
    const int NA = BB * AA;
    const int labels4 = NA / 4;
    const int boxes4_end = labels4 + NA;
    const int total4 = labels4 + NA + NA * 20 + NA / 4;  // 5,779,200
    nfloat4* o4 = reinterpret_cast<nfloat4*>(out);
    for (int idx = (g << 8) + t; idx < total4; idx += 1024 * 256) {
      nfloat4 v;
      if (idx < labels4) {
        const int fb = (idx * 4) / AA;
        int lab = gt_labels[fb * NBB];
        lab = min(max(lab, 0), 80);
        const float lf = (float)lab;
        v = (nfloat4){lf, lf, lf, lf};
      } else if (idx < boxes4_end) {
        const int aidx = idx - labels4;
        const int fb = aidx / AA;
        v = *reinterpret_cast<const nfloat4*>(gt_boxes + (size_t)fb * NBB * 4);
      } else {
        v = (nfloat4){0.f, 0.f, 0.f, 0.f};
      }
      __builtin_nontemporal_store(v, &o4[idx]);
    }
  }

  // ---- candidate enumeration + top-10 ----
  const float gx0 = gt_boxes[g * 4 + 0], gy0 = gt_boxes[g * 4 + 1];
  const float gx1 = gt_boxes[g * 4 + 2], gy1 = gt_boxes[g * 4 + 3];
  const int cls = gt_labels[g];
  const bool valid = (gt_mask[g] != 0);
  const float ga1 = (gx1 - gx0) * (gy1 - gy0);

  unsigned long long tkkey[TOPKN];
#pragma unroll
  for (int k = 0; k < TOPKN; k++) tkkey[k] = 0ull;

  if (valid) {
    const int strides[3] = {8, 16, 32};
    const int grids[3] = {80, 40, 20};
    const int offs[3] = {0, 6400, 8000};
    for (int lvl = 0; lvl < 3; lvl++) {
      const float s = (float)strides[lvl];
      const int n = grids[lvl], off = offs[lvl];
      int lx = max(0, (int)floorf(gx0 / s - 0.5f) - 1);
      int hx = min(n - 1, (int)ceilf(gx1 / s - 0.5f) + 1);
      int ly = max(0, (int)floorf(gy0 / s - 0.5f) - 1);
      int hy = min(n - 1, (int)ceilf(gy1 / s - 0.5f) + 1);
      if (hx < lx || hy < ly) continue;
      const int w = hx - lx + 1;
      const int m = w * (hy - ly + 1);
      for (int i = t; i < m; i += 256) {
        const int ix = lx + i % w;
        const int iy = ly + i / w;
        const float apx = ((float)ix + 0.5f) * s;
        const float apy = ((float)iy + 0.5f) * s;
        const float d = fminf(fminf(apx - gx0, apy - gy0),
                              fminf(gx1 - apx, gy1 - apy));
        if (!(d > 1e-8f)) continue;
        const int a = off + iy * n + ix;
        const float* pb = pred_boxes + ((size_t)b * AA + a) * 4;
        const float p0 = pb[0], p1 = pb[1], p2 = pb[2], p3 = pb[3];
        const float iw = fmaxf(fminf(gx1, p2) - fmaxf(gx0, p0), 0.0f);
        const float ih = fmaxf(fminf(gy1, p3) - fmaxf(gy0, p1), 0.0f);
        const float inter = iw * ih;
        const float a2 = (p2 - p0) * (p3 - p1);
        const float iou = fmaxf(inter / (ga1 + a2 - inter + 1e-10f), 0.0f);
        const float sc = pred_scores[((size_t)b * AA + a) * CC + cls];
        const float i2 = iou * iou;
        const float align_v = sc * i2 * i2 * i2;
        const unsigned long long key =
            ((unsigned long long)__float_as_uint(align_v) << 32) |
            (unsigned int)(AA - a);
        if (key > tkkey[TOPKN - 1]) {
          tkkey[TOPKN - 1] = key;
#pragma unroll
          for (int k = TOPKN - 1; k > 0; k--) {
            if (tkkey[k] > tkkey[k - 1]) {
              unsigned long long tmp = tkkey[k];
              tkkey[k] = tkkey[k - 1];
              tkkey[k - 1] = tmp;
            }
          }
        }
      }
    }
  }

  __shared__ unsigned long long s_key[256][TOPKN + 1];  // stride 88B: free
#pragma unroll
  for (int k = 0; k < TOPKN; k++) s_key[t][k] = tkkey[k];
  __syncthreads();

  for (int stride = 128; stride >= 1; stride >>= 1) {
    if (t < stride) {
      unsigned long long mk[TOPKN];
      int p = 0, q = 0;
#pragma unroll
      for (int k = 0; k < TOPKN; k++) {
        const unsigned long long k1 = s_key[t][p], k2 = s_key[t + stride][q];
        if (k1 >= k2) { mk[k] = k1; p++; } else { mk[k] = k2; q++; }
      }
#pragma unroll
      for (int k = 0; k < TOPKN; k++) s_key[t][k] = mk[k];
    }
    __syncthreads();
  }

  if (t < TOPKN) {
    const unsigned long long key = s_key[0][t];
    tk[g * TOPKN + t] = (key != 0ull) ? (AA - (int)(key & 0xffffffffu)) : -1;
  }
}

// ===========================================================================
// K2 (merged resolve+scatter): grid (NBB, BB) x 64t. Block (j,b):
//  P1: evaluate ALL 320 candidate entries of batch b (5/thread): cnt via
//      LDS-broadcast scan; cnt==1 -> own row q; cnt>1 -> first-max argmax_j
//      over all 32 gts (reference semantics). Results in LDS.
//  P2: posA/posI for all 32 rows reduced IN LDS (t<32 scans 320 entries;
//      duplicate conflicted entries are value-identical -> max unaffected).
//  P3: scatter row j's <=10 entries over the defaults (labels/box/score/fg).
// No global atomics, no pos workspace, one fewer kernel than R16.
// ===========================================================================
__global__ __launch_bounds__(64) void resolve_scatter_kernel(
    const float* __restrict__ pred_scores, const float* __restrict__ pred_boxes,
    const float* __restrict__ anchor_points, const int* __restrict__ gt_labels,
    const float* __restrict__ gt_boxes, const int* __restrict__ gt_mask,
    const int* __restrict__ tk, float* __restrict__ out) {
  const int j = blockIdx.x, b = blockIdx.y, t = threadIdx.x;

  __shared__ float sbox[NBB][4];
  __shared__ int scls[NBB];
  __shared__ int svalid[NBB];
  __shared__ int sa[NCAND];
  __shared__ int ejj[NCAND];
  __shared__ float eal[NCAND];
  __shared__ float eiu[NCAND];
  __shared__ float sposA[NBB];
  __shared__ float sposI[NBB];

  if (t < NBB) {
    const int g = b * NBB + t;
    sbox[t][0] = gt_boxes[g * 4 + 0];
    sbox[t][1] = gt_boxes[g * 4 + 1];
    sbox[t][2] = gt_boxes[g * 4 + 2];
    sbox[t][3] = gt_boxes[g * 4 + 3];
    scls[t] = gt_labels[g];
    svalid[t] = (gt_mask[g] != 0) ? 1 : 0;
  }
  for (int e = t; e < NCAND; e += 64) sa[e] = tk[b * NCAND + e];
  __syncthreads();

  // P1: evaluate all entries
  for (int e = t; e < NCAND; e += 64) {
    const int a = sa[e];
    if (a < 0) { ejj[e] = -1; continue; }
    const int q = e / TOPKN;

    int cnt = 0;
    for (int i = 0; i < NCAND; i++) cnt += (sa[i] == a) ? 1 : 0;

    const float apx = anchor_points[a * 2 + 0];
    const float apy = anchor_points[a * 2 + 1];
    const float* pb = pred_boxes + ((size_t)b * AA + a) * 4;
    const float p0 = pb[0], p1 = pb[1], p2 = pb[2], p3 = pb[3];
    const float a2 = (p2 - p0) * (p3 - p1);

    int jj;
    float iou_f;
    if (cnt == 1) {
      jj = q;
      const float gx0 = sbox[q][0], gy0 = sbox[q][1];
      const float gx1 = sbox[q][2], gy1 = sbox[q][3];
      const float iw = fmaxf(fminf(gx1, p2) - fmaxf(gx0, p0), 0.0f);
      const float ih = fmaxf(fminf(gy1, p3) - fmaxf(gy0, p1), 0.0f);
      const float inter = iw * ih;
      const float a1 = (gx1 - gx0) * (gy1 - gy0);
      iou_f = fmaxf(inter / (a1 + a2 - inter + 1e-10f), 0.0f);
    } else {
      float best_iou = -1.0f;
      int best_j = 0;
      for (int jq = 0; jq < NBB; jq++) {
        const float gx0 = sbox[jq][0], gy0 = sbox[jq][1];
        const float gx1 = sbox[jq][2], gy1 = sbox[jq][3];
        const float d = fminf(fminf(apx - gx0, apy - gy0),
                              fminf(gx1 - apx, gy1 - apy));
        float iou = 0.0f;
        if (svalid[jq] && d > 1e-8f) {
          const float iw = fmaxf(fminf(gx1, p2) - fmaxf(gx0, p0), 0.0f);
          const float ih = fmaxf(fminf(gy1, p3) - fmaxf(gy0, p1), 0.0f);
          const float inter = iw * ih;
          const float a1 = (gx1 - gx0) * (gy1 - gy0);
          iou = fmaxf(inter / (a1 + a2 - inter + 1e-10f), 0.0f);
        }
        if (iou > best_iou) { best_iou = iou; best_j = jq; }  // first-max
      }
      jj = best_j;
      iou_f = best_iou;
    }

    const float sc = pred_scores[((size_t)b * AA + a) * CC + scls[jj]];
    const float i2 = iou_f * iou_f;
    ejj[e] = jj;
    eal[e] = sc * i2 * i2 * i2;
    eiu[e] = iou_f;
  }
  __syncthreads();

  // P2: per-row pos maxima in LDS (uniform-address scans -> broadcast)
  if (t < NBB) {
    float mA = 0.0f, mI = 0.0f;
    for (int i = 0; i < NCAND; i++) {
      if (ejj[i] == t) {
        mA = fmaxf(mA, eal[i]);
        mI = fmaxf(mI, eiu[i]);
      }
    }
    sposA[t] = mA;
    sposI[t] = mI;
  }
  __syncthreads();

  // P3: scatter this block's row entries
  if (t < TOPKN) {
    const int e = j * TOPKN + t;
    const int a = sa[e];
    if (a >= 0) {
      const int jj = ejj[e];
      const float norm = eal[e] * sposI[jj] / (sposA[jj] + 1e-8f);
      int label = scls[jj];
      label = min(max(label, 0), 80);
      const size_t aidx = (size_t)b * AA + a;

      out[aidx] = (float)label;                                       // labels
      *reinterpret_cast<float4*>(out + (size_t)BB * AA + aidx * 4) =  // boxes
          *reinterpret_cast<const float4*>(&sbox[jj][0]);
      if (label < CC)
        out[(size_t)BB * AA * 5 + aidx * CC + label] = norm;          // scores
      out[(size_t)BB * AA * 85 + aidx] = 1.0f;                        // fg
    }
  }
}

// ===========================================================================
extern "C" void kernel_launch(void* const* d_in, const int* in_sizes, int n_in,
                              void* d_out, int out_size, void* d_ws, size_t ws_size,
                              hipStream_t stream) {
  const float* pred_scores = (const float*)d_in[0];
  const float* pred_boxes = (const float*)d_in[1];
  const float* anchor_points = (const float*)d_in[2];
  const int* gt_labels = (const int*)d_in[3];
  const float* gt_boxes = (const float*)d_in[4];
  const int* gt_mask = (const int*)d_in[5];
  float* out = (float*)d_out;
  char* ws = (char*)d_ws;

  int* tk = (int*)ws;  // BB*NBB*TOPKN ints = 40 KB

  dim3 g1(NBB, BB);
  gt_topk_kernel<<<g1, 256, 0, stream>>>(pred_scores, pred_boxes, gt_labels,
                                         gt_boxes, gt_mask, tk, out);

  dim3 g2(NBB, BB);
  resolve_scatter_kernel<<<g2, 64, 0, stream>>>(
      pred_scores, pred_boxes, anchor_points, gt_labels, gt_boxes, gt_mask,
      tk, out);
}

// Round 19
// 50.400 us; speedup vs baseline: 2.0184x; 2.0184x over previous
//
#include <hip/hip_runtime.h>
#include <cstdint>
#include <cstddef>

#define BB 32
#define AA 8400
#define NBB 32
#define CC 80
#define TOPKN 10

// native clang vector for __builtin_nontemporal_store (HIP float4 is a
// class type the builtin rejects; this alias is layout-identical)
typedef float nfloat4 __attribute__((ext_vector_type(4)));

// ===========================================================================
// K1 (+fused NT default-fill): per (b,j) block (256t).
// (1) Streams the "unassigned" default output for its 1/1024 slice of the
//     92.5 MB output via NON-TEMPORAL float4 stores (write-once data:
//     bypass L2, keep it for the gathers -- R18 subtraction showed ~13 us
//     K1 gain vs regular stores). Regions (float4 idx, NA=BB*AA):
//     [0,NA/4) labels=clip(gt_labels[b,0]) | [NA/4,NA/4+NA) boxes=gt_boxes[b,0]
//     | scores zeros | fg zeros.
// (2) Analytic candidate enumeration (3-level anchor grid, bit-exact
//     (ix+0.5)*s recompute, exact d>1e-8 re-test) + block top-10 via padded
//     LDS merge ([256][11] u64 rows, stride 88B -> free 2-way aliasing).
//     key = align_bits<<32 | (8400-a): lax.top_k tie semantics.
// Also zeroes posA/posI (t==0).
// ===========================================================================
__global__ __launch_bounds__(256) void gt_topk_kernel(
    const float* __restrict__ pred_scores, const float* __restrict__ pred_boxes,
    const int* __restrict__ gt_labels, const float* __restrict__ gt_boxes,
    const int* __restrict__ gt_mask,
    int* __restrict__ tk, int* __restrict__ posA, int* __restrict__ posI,
    float* __restrict__ out) {
  const int j = blockIdx.x, b = blockIdx.y, t = threadIdx.x;
  const int g = b * NBB + j;
  if (t == 0) { posA[g] = 0; posI[g] = 0; }

  // ---- fused default-fill (write-only NT stream) ----
  {
    const int NA = BB * AA;
    const int labels4 = NA / 4;
    const int boxes4_end = labels4 + NA;
    const int total4 = labels4 + NA + NA * 20 + NA / 4;  // 5,779,200
    nfloat4* o4 = reinterpret_cast<nfloat4*>(out);
    for (int idx = (g << 8) + t; idx < total4; idx += 1024 * 256) {
      nfloat4 v;
      if (idx < labels4) {
        const int fb = (idx * 4) / AA;
        int lab = gt_labels[fb * NBB];
        lab = min(max(lab, 0), 80);
        const float lf = (float)lab;
        v = (nfloat4){lf, lf, lf, lf};
      } else if (idx < boxes4_end) {
        const int aidx = idx - labels4;
        const int fb = aidx / AA;
        v = *reinterpret_cast<const nfloat4*>(gt_boxes + (size_t)fb * NBB * 4);
      } else {
        v = (nfloat4){0.f, 0.f, 0.f, 0.f};
      }
      __builtin_nontemporal_store(v, &o4[idx]);
    }
  }

  // ---- candidate enumeration + top-10 ----
  const float gx0 = gt_boxes[g * 4 + 0], gy0 = gt_boxes[g * 4 + 1];
  const float gx1 = gt_boxes[g * 4 + 2], gy1 = gt_boxes[g * 4 + 3];
  const int cls = gt_labels[g];
  const bool valid = (gt_mask[g] != 0);
  const float ga1 = (gx1 - gx0) * (gy1 - gy0);

  unsigned long long tkkey[TOPKN];
#pragma unroll
  for (int k = 0; k < TOPKN; k++) tkkey[k] = 0ull;

  if (valid) {
    const int strides[3] = {8, 16, 32};
    const int grids[3] = {80, 40, 20};
    const int offs[3] = {0, 6400, 8000};
    for (int lvl = 0; lvl < 3; lvl++) {
      const float s = (float)strides[lvl];
      const int n = grids[lvl], off = offs[lvl];
      int lx = max(0, (int)floorf(gx0 / s - 0.5f) - 1);
      int hx = min(n - 1, (int)ceilf(gx1 / s - 0.5f) + 1);
      int ly = max(0, (int)floorf(gy0 / s - 0.5f) - 1);
      int hy = min(n - 1, (int)ceilf(gy1 / s - 0.5f) + 1);
      if (hx < lx || hy < ly) continue;
      const int w = hx - lx + 1;
      const int m = w * (hy - ly + 1);
      for (int i = t; i < m; i += 256) {
        const int ix = lx + i % w;
        const int iy = ly + i / w;
        const float apx = ((float)ix + 0.5f) * s;
        const float apy = ((float)iy + 0.5f) * s;
        const float d = fminf(fminf(apx - gx0, apy - gy0),
                              fminf(gx1 - apx, gy1 - apy));
        if (!(d > 1e-8f)) continue;
        const int a = off + iy * n + ix;
        const float* pb = pred_boxes + ((size_t)b * AA + a) * 4;
        const float p0 = pb[0], p1 = pb[1], p2 = pb[2], p3 = pb[3];
        const float iw = fmaxf(fminf(gx1, p2) - fmaxf(gx0, p0), 0.0f);
        const float ih = fmaxf(fminf(gy1, p3) - fmaxf(gy0, p1), 0.0f);
        const float inter = iw * ih;
        const float a2 = (p2 - p0) * (p3 - p1);
        const float iou = fmaxf(inter / (ga1 + a2 - inter + 1e-10f), 0.0f);
        const float sc = pred_scores[((size_t)b * AA + a) * CC + cls];
        const float i2 = iou * iou;
        const float align_v = sc * i2 * i2 * i2;
        const unsigned long long key =
            ((unsigned long long)__float_as_uint(align_v) << 32) |
            (unsigned int)(AA - a);
        if (key > tkkey[TOPKN - 1]) {
          tkkey[TOPKN - 1] = key;
#pragma unroll
          for (int k = TOPKN - 1; k > 0; k--) {
            if (tkkey[k] > tkkey[k - 1]) {
              unsigned long long tmp = tkkey[k];
              tkkey[k] = tkkey[k - 1];
              tkkey[k - 1] = tmp;
            }
          }
        }
      }
    }
  }

  __shared__ unsigned long long s_key[256][TOPKN + 1];  // stride 88B: free
#pragma unroll
  for (int k = 0; k < TOPKN; k++) s_key[t][k] = tkkey[k];
  __syncthreads();

  for (int stride = 128; stride >= 1; stride >>= 1) {
    if (t < stride) {
      unsigned long long mk[TOPKN];
      int p = 0, q = 0;
#pragma unroll
      for (int k = 0; k < TOPKN; k++) {
        const unsigned long long k1 = s_key[t][p], k2 = s_key[t + stride][q];
        if (k1 >= k2) { mk[k] = k1; p++; } else { mk[k] = k2; q++; }
      }
#pragma unroll
      for (int k = 0; k < TOPKN; k++) s_key[t][k] = mk[k];
    }
    __syncthreads();
  }

  if (t < TOPKN) {
    const unsigned long long key = s_key[0][t];
    tk[g * TOPKN + t] = (key != 0ull) ? (AA - (int)(key & 0xffffffffu)) : -1;
  }
}

// ===========================================================================
// K2: grid (NBB, BB) x 64t (R16-validated). Block (j,b) resolves ONLY gt
// row j's 10 candidates against the batch's 320-entry LDS list
// (wave-uniform scan = broadcast). cnt==1 -> row j; cnt>1 -> first-max
// argmax_j over all 32 gts. Compact results (resj/resAl); atomicMax pos.
// ===========================================================================
__global__ __launch_bounds__(64) void assign_sparse_kernel(
    const float* __restrict__ pred_scores, const float* __restrict__ pred_boxes,
    const float* __restrict__ anchor_points, const int* __restrict__ gt_labels,
    const float* __restrict__ gt_boxes, const int* __restrict__ gt_mask,
    const int* __restrict__ tk,
    int* __restrict__ resj, float* __restrict__ resAl,
    int* __restrict__ posA, int* __restrict__ posI) {
  const int j = blockIdx.x, b = blockIdx.y, t = threadIdx.x;

  __shared__ float sbox[NBB][4];
  __shared__ int scls[NBB];
  __shared__ int svalid[NBB];
  __shared__ int sa[NBB * TOPKN];

  if (t < NBB) {
    const int g = b * NBB + t;
    sbox[t][0] = gt_boxes[g * 4 + 0];
    sbox[t][1] = gt_boxes[g * 4 + 1];
    sbox[t][2] = gt_boxes[g * 4 + 2];
    sbox[t][3] = gt_boxes[g * 4 + 3];
    scls[t] = gt_labels[g];
    svalid[t] = (gt_mask[g] != 0) ? 1 : 0;
  }
  for (int e = t; e < NBB * TOPKN; e += 64) sa[e] = tk[b * NBB * TOPKN + e];
  __syncthreads();

  if (t >= TOPKN) return;  // no barriers below
  const int a = sa[j * TOPKN + t];
  if (a < 0) return;

  int cnt = 0;
  for (int q = 0; q < NBB * TOPKN; q++) cnt += (sa[q] == a) ? 1 : 0;

  const float apx = anchor_points[a * 2 + 0];
  const float apy = anchor_points[a * 2 + 1];
  const float* pb = pred_boxes + ((size_t)b * AA + a) * 4;
  const float p0 = pb[0], p1 = pb[1], p2 = pb[2], p3 = pb[3];
  const float a2 = (p2 - p0) * (p3 - p1);

  int jj;
  float iou_f;
  if (cnt == 1) {
    jj = j;
    const float gx0 = sbox[j][0], gy0 = sbox[j][1];
    const float gx1 = sbox[j][2], gy1 = sbox[j][3];
    const float iw = fmaxf(fminf(gx1, p2) - fmaxf(gx0, p0), 0.0f);
    const float ih = fmaxf(fminf(gy1, p3) - fmaxf(gy0, p1), 0.0f);
    const float inter = iw * ih;
    const float a1 = (gx1 - gx0) * (gy1 - gy0);
    iou_f = fmaxf(inter / (a1 + a2 - inter + 1e-10f), 0.0f);
  } else {
    float best_iou = -1.0f;
    int best_j = 0;
    for (int jq = 0; jq < NBB; jq++) {
      const float gx0 = sbox[jq][0], gy0 = sbox[jq][1];
      const float gx1 = sbox[jq][2], gy1 = sbox[jq][3];
      const float d = fminf(fminf(apx - gx0, apy - gy0),
                            fminf(gx1 - apx, gy1 - apy));
      float iou = 0.0f;
      if (svalid[jq] && d > 1e-8f) {
        const float iw = fmaxf(fminf(gx1, p2) - fmaxf(gx0, p0), 0.0f);
        const float ih = fmaxf(fminf(gy1, p3) - fmaxf(gy0, p1), 0.0f);
        const float inter = iw * ih;
        const float a1 = (gx1 - gx0) * (gy1 - gy0);
        iou = fmaxf(inter / (a1 + a2 - inter + 1e-10f), 0.0f);
      }
      if (iou > best_iou) { best_iou = iou; best_j = jq; }  // first-max
    }
    jj = best_j;
    iou_f = best_iou;
  }

  const float sc = pred_scores[((size_t)b * AA + a) * CC + scls[jj]];
  const float i2 = iou_f * iou_f;
  const float align_v = sc * i2 * i2 * i2;
  const int e = (b * NBB + j) * TOPKN + t;
  resj[e] = jj;
  resAl[e] = align_v;
  atomicMax(&posA[b * NBB + jj], __float_as_int(align_v));
  atomicMax(&posI[b * NBB + jj], __float_as_int(iou_f));
}

// ===========================================================================
// K3b: sparse scatter of assigned-anchor outputs over the defaults
// (R16-validated). One thread per candidate entry (10240); duplicates
// value-identical.
// ===========================================================================
__global__ __launch_bounds__(256) void scatter_out_kernel(
    const int* __restrict__ gt_labels, const float* __restrict__ gt_boxes,
    const int* __restrict__ tk, const int* __restrict__ resj,
    const float* __restrict__ resAl, const int* __restrict__ posA,
    const int* __restrict__ posI, float* __restrict__ out) {
  const int e = blockIdx.x * 256 + threadIdx.x;
  if (e >= BB * NBB * TOPKN) return;
  const int a = tk[e];
  if (a < 0) return;
  const int b = e / (NBB * TOPKN);
  const int jj = resj[e];
  const float align_v = resAl[e];
  const float pa = __int_as_float(posA[b * NBB + jj]);
  const float pi = __int_as_float(posI[b * NBB + jj]);
  const float norm = align_v * pi / (pa + 1e-8f);
  int label = gt_labels[b * NBB + jj];
  label = min(max(label, 0), 80);
  const size_t aidx = (size_t)b * AA + a;

  out[aidx] = (float)label;                                       // labels
  *reinterpret_cast<float4*>(out + (size_t)BB * AA + aidx * 4) =  // boxes
      *reinterpret_cast<const float4*>(gt_boxes + ((size_t)b * NBB + jj) * 4);
  if (label < CC)
    out[(size_t)BB * AA * 5 + aidx * CC + label] = norm;          // scores
  out[(size_t)BB * AA * 85 + aidx] = 1.0f;                        // fg
}

// ===========================================================================
extern "C" void kernel_launch(void* const* d_in, const int* in_sizes, int n_in,
                              void* d_out, int out_size, void* d_ws, size_t ws_size,
                              hipStream_t stream) {
  const float* pred_scores = (const float*)d_in[0];
  const float* pred_boxes = (const float*)d_in[1];
  const float* anchor_points = (const float*)d_in[2];
  const int* gt_labels = (const int*)d_in[3];
  const float* gt_boxes = (const float*)d_in[4];
  const int* gt_mask = (const int*)d_in[5];
  float* out = (float*)d_out;
  char* ws = (char*)d_ws;

  // workspace: tk | posA | posI | resj | resAl (all small)
  const size_t off_tk = 0;                                  // 40 KB
  const size_t off_posA = off_tk + (size_t)BB * NBB * TOPKN * 4;
  const size_t off_posI = off_posA + 4096;
  const size_t off_resj = off_posI + 4096;                  // 40 KB
  const size_t off_resAl = off_resj + (size_t)BB * NBB * TOPKN * 4;

  int* tk = (int*)(ws + off_tk);
  int* posA = (int*)(ws + off_posA);
  int* posI = (int*)(ws + off_posI);
  int* resj = (int*)(ws + off_resj);
  float* resAl = (float*)(ws + off_resAl);

  dim3 g1(NBB, BB);
  gt_topk_kernel<<<g1, 256, 0, stream>>>(pred_scores, pred_boxes, gt_labels,
                                         gt_boxes, gt_mask, tk, posA, posI,
                                         out);

  dim3 g2(NBB, BB);
  assign_sparse_kernel<<<g2, 64, 0, stream>>>(
      pred_scores, pred_boxes, anchor_points, gt_labels, gt_boxes, gt_mask,
      tk, resj, resAl, posA, posI);

  const int ncand = BB * NBB * TOPKN;
  scatter_out_kernel<<<(ncand + 255) / 256, 256, 0, stream>>>(
      gt_labels, gt_boxes, tk, resj, resAl, posA, posI, out);
}

// Round 20
// 47.434 us; speedup vs baseline: 2.1446x; 1.0625x over previous
//
#include <hip/hip_runtime.h>
#include <cstdint>
#include <cstddef>

#define BB 32
#define AA 8400
#define NBB 32
#define CC 80
#define TOPKN 10

// native clang vector for __builtin_nontemporal_store (HIP float4 is a
// class type the builtin rejects; this alias is layout-identical)
typedef float nfloat4 __attribute__((ext_vector_type(4)));

// ===========================================================================
// K1 (block-specialized): grid (NBB, BB, 2) x 256t.
//  z=1 blocks: ONLY stream the "unassigned" default output (1/1024 slice of
//    92.5 MB, NT float4 stores). Store-bound.
//  z=0 blocks: ONLY candidate enumeration + top-10 for gt (j,b). Latency-
//    bound gathers.
//  Specialization replaces R16's program-order fusion (store phase then
//  gather phase serialized within each wave); co-resident store-waves and
//  gather-waves overlap at the CU scheduler level instead.
// Fill regions (float4 idx, NA=BB*AA): [0,NA/4) labels=clip(gt_labels[b,0])
// | [NA/4,NA/4+NA) boxes=gt_boxes[b,0] | scores zeros | fg zeros.
// Enum: 3-level anchor grid (bit-exact (ix+0.5)*s), exact d>1e-8 re-test,
// block top-10 via padded LDS merge ([256][11] u64, stride 88B).
// key = align_bits<<32 | (8400-a): lax.top_k tie semantics.
// ===========================================================================
__global__ __launch_bounds__(256) void gt_topk_kernel(
    const float* __restrict__ pred_scores, const float* __restrict__ pred_boxes,
    const int* __restrict__ gt_labels, const float* __restrict__ gt_boxes,
    const int* __restrict__ gt_mask,
    int* __restrict__ tk, int* __restrict__ posA, int* __restrict__ posI,
    float* __restrict__ out) {
  const int j = blockIdx.x, b = blockIdx.y, t = threadIdx.x;
  const int g = b * NBB + j;

  if (blockIdx.z == 1) {
    // ---- fill-only blocks (write-only NT stream) ----
    const int NA = BB * AA;
    const int labels4 = NA / 4;
    const int boxes4_end = labels4 + NA;
    const int total4 = labels4 + NA + NA * 20 + NA / 4;  // 5,779,200
    nfloat4* o4 = reinterpret_cast<nfloat4*>(out);
    for (int idx = (g << 8) + t; idx < total4; idx += 1024 * 256) {
      nfloat4 v;
      if (idx < labels4) {
        const int fb = (idx * 4) / AA;
        int lab = gt_labels[fb * NBB];
        lab = min(max(lab, 0), 80);
        const float lf = (float)lab;
        v = (nfloat4){lf, lf, lf, lf};
      } else if (idx < boxes4_end) {
        const int aidx = idx - labels4;
        const int fb = aidx / AA;
        v = *reinterpret_cast<const nfloat4*>(gt_boxes + (size_t)fb * NBB * 4);
      } else {
        v = (nfloat4){0.f, 0.f, 0.f, 0.f};
      }
      __builtin_nontemporal_store(v, &o4[idx]);
    }
    return;
  }

  // ---- enum-only blocks ----
  if (t == 0) { posA[g] = 0; posI[g] = 0; }

  const float gx0 = gt_boxes[g * 4 + 0], gy0 = gt_boxes[g * 4 + 1];
  const float gx1 = gt_boxes[g * 4 + 2], gy1 = gt_boxes[g * 4 + 3];
  const int cls = gt_labels[g];
  const bool valid = (gt_mask[g] != 0);
  const float ga1 = (gx1 - gx0) * (gy1 - gy0);

  unsigned long long tkkey[TOPKN];
#pragma unroll
  for (int k = 0; k < TOPKN; k++) tkkey[k] = 0ull;

  if (valid) {
    const int strides[3] = {8, 16, 32};
    const int grids[3] = {80, 40, 20};
    const int offs[3] = {0, 6400, 8000};
    for (int lvl = 0; lvl < 3; lvl++) {
      const float s = (float)strides[lvl];
      const int n = grids[lvl], off = offs[lvl];
      int lx = max(0, (int)floorf(gx0 / s - 0.5f) - 1);
      int hx = min(n - 1, (int)ceilf(gx1 / s - 0.5f) + 1);
      int ly = max(0, (int)floorf(gy0 / s - 0.5f) - 1);
      int hy = min(n - 1, (int)ceilf(gy1 / s - 0.5f) + 1);
      if (hx < lx || hy < ly) continue;
      const int w = hx - lx + 1;
      const int m = w * (hy - ly + 1);
      for (int i = t; i < m; i += 256) {
        const int ix = lx + i % w;
        const int iy = ly + i / w;
        const float apx = ((float)ix + 0.5f) * s;
        const float apy = ((float)iy + 0.5f) * s;
        const float d = fminf(fminf(apx - gx0, apy - gy0),
                              fminf(gx1 - apx, gy1 - apy));
        if (!(d > 1e-8f)) continue;
        const int a = off + iy * n + ix;
        const float* pb = pred_boxes + ((size_t)b * AA + a) * 4;
        const float p0 = pb[0], p1 = pb[1], p2 = pb[2], p3 = pb[3];
        const float iw = fmaxf(fminf(gx1, p2) - fmaxf(gx0, p0), 0.0f);
        const float ih = fmaxf(fminf(gy1, p3) - fmaxf(gy0, p1), 0.0f);
        const float inter = iw * ih;
        const float a2 = (p2 - p0) * (p3 - p1);
        const float iou = fmaxf(inter / (ga1 + a2 - inter + 1e-10f), 0.0f);
        const float sc = pred_scores[((size_t)b * AA + a) * CC + cls];
        const float i2 = iou * iou;
        const float align_v = sc * i2 * i2 * i2;
        const unsigned long long key =
            ((unsigned long long)__float_as_uint(align_v) << 32) |
            (unsigned int)(AA - a);
        if (key > tkkey[TOPKN - 1]) {
          tkkey[TOPKN - 1] = key;
#pragma unroll
          for (int k = TOPKN - 1; k > 0; k--) {
            if (tkkey[k] > tkkey[k - 1]) {
              unsigned long long tmp = tkkey[k];
              tkkey[k] = tkkey[k - 1];
              tkkey[k - 1] = tmp;
            }
          }
        }
      }
    }
  }

  __shared__ unsigned long long s_key[256][TOPKN + 1];  // stride 88B: free
#pragma unroll
  for (int k = 0; k < TOPKN; k++) s_key[t][k] = tkkey[k];
  __syncthreads();

  for (int stride = 128; stride >= 1; stride >>= 1) {
    if (t < stride) {
      unsigned long long mk[TOPKN];
      int p = 0, q = 0;
#pragma unroll
      for (int k = 0; k < TOPKN; k++) {
        const unsigned long long k1 = s_key[t][p], k2 = s_key[t + stride][q];
        if (k1 >= k2) { mk[k] = k1; p++; } else { mk[k] = k2; q++; }
      }
#pragma unroll
      for (int k = 0; k < TOPKN; k++) s_key[t][k] = mk[k];
    }
    __syncthreads();
  }

  if (t < TOPKN) {
    const unsigned long long key = s_key[0][t];
    tk[g * TOPKN + t] = (key != 0ull) ? (AA - (int)(key & 0xffffffffu)) : -1;
  }
}

// ===========================================================================
// K2: grid (NBB, BB) x 64t (R16-validated). Block (j,b) resolves ONLY gt
// row j's 10 candidates against the batch's 320-entry LDS list
// (wave-uniform scan = broadcast). cnt==1 -> row j; cnt>1 -> first-max
// argmax_j over all 32 gts. Compact results (resj/resAl); atomicMax pos.
// ===========================================================================
__global__ __launch_bounds__(64) void assign_sparse_kernel(
    const float* __restrict__ pred_scores, const float* __restrict__ pred_boxes,
    const float* __restrict__ anchor_points, const int* __restrict__ gt_labels,
    const float* __restrict__ gt_boxes, const int* __restrict__ gt_mask,
    const int* __restrict__ tk,
    int* __restrict__ resj, float* __restrict__ resAl,
    int* __restrict__ posA, int* __restrict__ posI) {
  const int j = blockIdx.x, b = blockIdx.y, t = threadIdx.x;

  __shared__ float sbox[NBB][4];
  __shared__ int scls[NBB];
  __shared__ int svalid[NBB];
  __shared__ int sa[NBB * TOPKN];

  if (t < NBB) {
    const int g = b * NBB + t;
    sbox[t][0] = gt_boxes[g * 4 + 0];
    sbox[t][1] = gt_boxes[g * 4 + 1];
    sbox[t][2] = gt_boxes[g * 4 + 2];
    sbox[t][3] = gt_boxes[g * 4 + 3];
    scls[t] = gt_labels[g];
    svalid[t] = (gt_mask[g] != 0) ? 1 : 0;
  }
  for (int e = t; e < NBB * TOPKN; e += 64) sa[e] = tk[b * NBB * TOPKN + e];
  __syncthreads();

  if (t >= TOPKN) return;  // no barriers below
  const int a = sa[j * TOPKN + t];
  if (a < 0) return;

  int cnt = 0;
  for (int q = 0; q < NBB * TOPKN; q++) cnt += (sa[q] == a) ? 1 : 0;

  const float apx = anchor_points[a * 2 + 0];
  const float apy = anchor_points[a * 2 + 1];
  const float* pb = pred_boxes + ((size_t)b * AA + a) * 4;
  const float p0 = pb[0], p1 = pb[1], p2 = pb[2], p3 = pb[3];
  const float a2 = (p2 - p0) * (p3 - p1);

  int jj;
  float iou_f;
  if (cnt == 1) {
    jj = j;
    const float gx0 = sbox[j][0], gy0 = sbox[j][1];
    const float gx1 = sbox[j][2], gy1 = sbox[j][3];
    const float iw = fmaxf(fminf(gx1, p2) - fmaxf(gx0, p0), 0.0f);
    const float ih = fmaxf(fminf(gy1, p3) - fmaxf(gy0, p1), 0.0f);
    const float inter = iw * ih;
    const float a1 = (gx1 - gx0) * (gy1 - gy0);
    iou_f = fmaxf(inter / (a1 + a2 - inter + 1e-10f), 0.0f);
  } else {
    float best_iou = -1.0f;
    int best_j = 0;
    for (int jq = 0; jq < NBB; jq++) {
      const float gx0 = sbox[jq][0], gy0 = sbox[jq][1];
      const float gx1 = sbox[jq][2], gy1 = sbox[jq][3];
      const float d = fminf(fminf(apx - gx0, apy - gy0),
                            fminf(gx1 - apx, gy1 - apy));
      float iou = 0.0f;
      if (svalid[jq] && d > 1e-8f) {
        const float iw = fmaxf(fminf(gx1, p2) - fmaxf(gx0, p0), 0.0f);
        const float ih = fmaxf(fminf(gy1, p3) - fmaxf(gy0, p1), 0.0f);
        const float inter = iw * ih;
        const float a1 = (gx1 - gx0) * (gy1 - gy0);
        iou = fmaxf(inter / (a1 + a2 - inter + 1e-10f), 0.0f);
      }
      if (iou > best_iou) { best_iou = iou; best_j = jq; }  // first-max
    }
    jj = best_j;
    iou_f = best_iou;
  }

  const float sc = pred_scores[((size_t)b * AA + a) * CC + scls[jj]];
  const float i2 = iou_f * iou_f;
  const float align_v = sc * i2 * i2 * i2;
  const int e = (b * NBB + j) * TOPKN + t;
  resj[e] = jj;
  resAl[e] = align_v;
  atomicMax(&posA[b * NBB + jj], __float_as_int(align_v));
  atomicMax(&posI[b * NBB + jj], __float_as_int(iou_f));
}

// ===========================================================================
// K3b: sparse scatter of assigned-anchor outputs over the defaults
// (R16-validated). One thread per candidate entry (10240); duplicates
// value-identical.
// ===========================================================================
__global__ __launch_bounds__(256) void scatter_out_kernel(
    const int* __restrict__ gt_labels, const float* __restrict__ gt_boxes,
    const int* __restrict__ tk, const int* __restrict__ resj,
    const float* __restrict__ resAl, const int* __restrict__ posA,
    const int* __restrict__ posI, float* __restrict__ out) {
  const int e = blockIdx.x * 256 + threadIdx.x;
  if (e >= BB * NBB * TOPKN) return;
  const int a = tk[e];
  if (a < 0) return;
  const int b = e / (NBB * TOPKN);
  const int jj = resj[e];
  const float align_v = resAl[e];
  const float pa = __int_as_float(posA[b * NBB + jj]);
  const float pi = __int_as_float(posI[b * NBB + jj]);
  const float norm = align_v * pi / (pa + 1e-8f);
  int label = gt_labels[b * NBB + jj];
  label = min(max(label, 0), 80);
  const size_t aidx = (size_t)b * AA + a;

  out[aidx] = (float)label;                                       // labels
  *reinterpret_cast<float4*>(out + (size_t)BB * AA + aidx * 4) =  // boxes
      *reinterpret_cast<const float4*>(gt_boxes + ((size_t)b * NBB + jj) * 4);
  if (label < CC)
    out[(size_t)BB * AA * 5 + aidx * CC + label] = norm;          // scores
  out[(size_t)BB * AA * 85 + aidx] = 1.0f;                        // fg
}

// ===========================================================================
extern "C" void kernel_launch(void* const* d_in, const int* in_sizes, int n_in,
                              void* d_out, int out_size, void* d_ws, size_t ws_size,
                              hipStream_t stream) {
  const float* pred_scores = (const float*)d_in[0];
  const float* pred_boxes = (const float*)d_in[1];
  const float* anchor_points = (const float*)d_in[2];
  const int* gt_labels = (const int*)d_in[3];
  const float* gt_boxes = (const float*)d_in[4];
  const int* gt_mask = (const int*)d_in[5];
  float* out = (float*)d_out;
  char* ws = (char*)d_ws;

  // workspace: tk | posA | posI | resj | resAl (all small)
  const size_t off_tk = 0;                                  // 40 KB
  const size_t off_posA = off_tk + (size_t)BB * NBB * TOPKN * 4;
  const size_t off_posI = off_posA + 4096;
  const size_t off_resj = off_posI + 4096;                  // 40 KB
  const size_t off_resAl = off_resj + (size_t)BB * NBB * TOPKN * 4;

  int* tk = (int*)(ws + off_tk);
  int* posA = (int*)(ws + off_posA);
  int* posI = (int*)(ws + off_posI);
  int* resj = (int*)(ws + off_resj);
  float* resAl = (float*)(ws + off_resAl);

  dim3 g1(NBB, BB, 2);  // z=0: enum blocks, z=1: fill blocks
  gt_topk_kernel<<<g1, 256, 0, stream>>>(pred_scores, pred_boxes, gt_labels,
                                         gt_boxes, gt_mask, tk, posA, posI,
                                         out);

  dim3 g2(NBB, BB);
  assign_sparse_kernel<<<g2, 64, 0, stream>>>(
      pred_scores, pred_boxes, anchor_points, gt_labels, gt_boxes, gt_mask,
      tk, resj, resAl, posA, posI);

  const int ncand = BB * NBB * TOPKN;
  scatter_out_kernel<<<(ncand + 255) / 256, 256, 0, stream>>>(
      gt_labels, gt_boxes, tk, resj, resAl, posA, posI, out);
}